// Round 7
// baseline (1661.647 us; speedup 1.0000x reference)
//
#include <hip/hip_runtime.h>
#include <cstdint>
#include <cstddef>

#define NN 30000
#define NE 60000
#define NG 1200
#define HID 384
#define EMB 768
#define OUTD 768
#define NEGS 0.01f

typedef _Float16 f16;
typedef _Float16 f16x8 __attribute__((ext_vector_type(8)));
typedef float f32x16 __attribute__((ext_vector_type(16)));

static __device__ __forceinline__ float leaky(float x){ return x > 0.f ? x : NEGS * x; }
static __device__ __forceinline__ float elu1(float x){ return x > 0.f ? x : (expf(x) - 1.f); }
static __device__ __forceinline__ float sigm(float x){ return 1.f / (1.f + expf(-x)); }

static __device__ __forceinline__ void atomicMaxF(float* a, float v){
  if (v >= 0.f) atomicMax((int*)a, __float_as_int(v));
  else atomicMin((unsigned int*)a, __float_as_uint(v));
}

// ---- fragment-packed (PF) layout for K=384 operands of mfma_32x32x16 ----
// chunk(rb,ks,lhi,l31) holds X[rb*32+l31][ks*16+lhi*8 .. +8]; wave reads 1KB contiguous.
static __device__ __forceinline__ size_t pf_idx(int row, int col){
  return (((((size_t)(row >> 5)) * 24 + (col >> 4)) * 2 + ((col >> 3) & 1)) * 32
          + (row & 31)) * 8 + (col & 7);
}
#define PF_RB_STRIDE 12288   // 24 ks * 64 lanes * 8 elems
#define PF_KS_STRIDE 512     // 64 lanes * 8 elems
#define PF_GATE_STRIDE 147456  // 12 rb * PF_RB_STRIDE  (= HID*HID)

// ---------------- f32 tiled GEMM (tables only) ----------------
__global__ __launch_bounds__(256) void k_gemm(
    const float* __restrict__ A, const float* __restrict__ B,
    const float* __restrict__ bias, float* __restrict__ C,
    int M, int N, int K, int act)
{
  __shared__ float As[16][65];
  __shared__ float Bs[16][65];
  const int tid = threadIdx.x;
  const int tx = tid & 15, ty = tid >> 4;
  const int row0 = blockIdx.y * 64, col0 = blockIdx.x * 64;
  const int ar = tid >> 2, ak = (tid & 3) << 2;
  const int bk = tid >> 4, bc = (tid & 15) << 2;
  float acc[4][4] = {};
  for (int k0 = 0; k0 < K; k0 += 16) {
    float4 av = make_float4(0.f, 0.f, 0.f, 0.f);
    if (row0 + ar < M)
      av = *(const float4*)(A + (size_t)(row0 + ar) * K + k0 + ak);
    As[ak + 0][ar] = av.x; As[ak + 1][ar] = av.y;
    As[ak + 2][ar] = av.z; As[ak + 3][ar] = av.w;
    float4 bv = *(const float4*)(B + (size_t)(k0 + bk) * N + col0 + bc);
    Bs[bk][bc + 0] = bv.x; Bs[bk][bc + 1] = bv.y;
    Bs[bk][bc + 2] = bv.z; Bs[bk][bc + 3] = bv.w;
    __syncthreads();
#pragma unroll
    for (int kk = 0; kk < 16; kk++) {
      float a[4], b[4];
#pragma unroll
      for (int i = 0; i < 4; i++) a[i] = As[kk][(ty << 2) + i];
#pragma unroll
      for (int j = 0; j < 4; j++) b[j] = Bs[kk][(tx << 2) + j];
#pragma unroll
      for (int i = 0; i < 4; i++)
#pragma unroll
        for (int j = 0; j < 4; j++)
          acc[i][j] = fmaf(a[i], b[j], acc[i][j]);
    }
    __syncthreads();
  }
#pragma unroll
  for (int i = 0; i < 4; i++) {
    int r = row0 + (ty << 2) + i;
    if (r >= M) continue;
#pragma unroll
    for (int j = 0; j < 4; j++) {
      int c = col0 + (tx << 2) + j;
      float v = acc[i][j];
      if (bias) v += bias[c];
      if (act == 1) v = leaky(v);
      else if (act == 2) v = elu1(v);
      else if (act == 3) v = fmaxf(v, 0.f);
      C[(size_t)r * N + c] = v;
    }
  }
}

// ------------- MFMA f16 GEMM v2, PF operands, no LDS -------------
// C = act(A[M,384] @ B[Nn,384]^T + bias). Block 256x128, 4 waves 2x2;
// wave = 128 rows x 64 cols (8 accs): 6 loads / 8 MFMAs per K-step.
__global__ __launch_bounds__(256) void k_hgemm(
    const f16* __restrict__ Apf, const f16* __restrict__ Bpf,
    const float* __restrict__ bias, float* __restrict__ Cf, f16* __restrict__ Ch,
    int M, int Nn, int act)
{
  const int nct = Nn >> 7;
  const int id = blockIdx.x;
  const int lane8 = id & 7, chunk = id >> 3;
  const int ct = chunk % nct, rg = chunk / nct;
  const int rt = rg * 8 + lane8;
  const int Mt = (M + 255) >> 8;
  if (rt >= Mt) return;
  const int r0 = rt * 256, n0 = ct * 128;
  const int tid = threadIdx.x;
  const int wid = tid >> 6, lane = tid & 63;
  const int wr = wid >> 1, wc = wid & 1;
  const int l31 = lane & 31, lhi = lane >> 5;
  const size_t lane_off = (size_t)(lhi * 32 + l31) * 8;
  const f16* pA[4]; const f16* pB[2];
#pragma unroll
  for (int i = 0; i < 4; i++)
    pA[i] = Apf + (size_t)(r0 / 32 + wr * 4 + i) * PF_RB_STRIDE + lane_off;
#pragma unroll
  for (int j = 0; j < 2; j++)
    pB[j] = Bpf + (size_t)(n0 / 32 + wc * 2 + j) * PF_RB_STRIDE + lane_off;
  f32x16 acc[4][2];
#pragma unroll
  for (int i = 0; i < 4; i++)
#pragma unroll
    for (int j = 0; j < 2; j++)
#pragma unroll
      for (int r = 0; r < 16; r++) acc[i][j][r] = 0.f;
#pragma unroll 2
  for (int ks = 0; ks < 24; ks++) {
    f16x8 af[4], bf[2];
#pragma unroll
    for (int i = 0; i < 4; i++) af[i] = *(const f16x8*)(pA[i] + (size_t)ks * PF_KS_STRIDE);
#pragma unroll
    for (int j = 0; j < 2; j++) bf[j] = *(const f16x8*)(pB[j] + (size_t)ks * PF_KS_STRIDE);
#pragma unroll
    for (int i = 0; i < 4; i++)
#pragma unroll
      for (int j = 0; j < 2; j++)
        acc[i][j] = __builtin_amdgcn_mfma_f32_32x32x16_f16(af[i], bf[j], acc[i][j], 0, 0, 0);
  }
#pragma unroll
  for (int i = 0; i < 4; i++)
#pragma unroll
    for (int j = 0; j < 2; j++) {
      int col = n0 + wc * 64 + j * 32 + l31;
      float bv = bias ? bias[col] : 0.f;
#pragma unroll
      for (int r = 0; r < 16; r++) {
        int row = r0 + wr * 128 + i * 32 + (r & 3) + 8 * (r >> 2) + 4 * lhi;
        if (row < M) {
          float v = acc[i][j][r] + bv;
          if (act == 1) v = leaky(v);
          else if (act == 2) v = elu1(v);
          else if (act == 3) v = fmaxf(v, 0.f);
          if (Cf) Cf[(size_t)row * Nn + col] = v;
          if (Ch) Ch[pf_idx(row, col)] = (f16)v;  // only used when Nn==HID
        }
      }
    }
}

// ------------- MFMA f16 fused GRU v2, PF operands, no LDS -------------
// Block 128 rows x 64 gate-cols, 4 waves 2x2; wave = 64 rows x 32 cols, 12 accs.
// Two sequential K-loops (U@Wi then H@Wh) to cap live registers at ~212.
__global__ __launch_bounds__(256) void k_gru_hgemm(
    const f16* __restrict__ Upf, const f16* __restrict__ Hpf, const float* __restrict__ Hsf,
    const f16* __restrict__ Wip, const f16* __restrict__ Whp,
    const float* __restrict__ bi, const float* __restrict__ bh,
    float* __restrict__ Xo, f16* __restrict__ Xoh, int M)
{
  const int id = blockIdx.x;
  const int lane8 = id & 7, chunk = id >> 3;
  const int ct = chunk % 6, rg = chunk / 6;
  const int rt = rg * 8 + lane8;
  const int Mt = (M + 127) >> 7;
  if (rt >= Mt) return;
  const int r0 = rt * 128, c0 = ct * 64;
  const int tid = threadIdx.x;
  const int wid = tid >> 6, lane = tid & 63;
  const int wr = wid >> 1, wc = wid & 1;
  const int l31 = lane & 31, lhi = lane >> 5;
  const size_t lane_off = (size_t)(lhi * 32 + l31) * 8;
  const f16* pU0 = Upf + (size_t)(r0 / 32 + wr * 2 + 0) * PF_RB_STRIDE + lane_off;
  const f16* pU1 = Upf + (size_t)(r0 / 32 + wr * 2 + 1) * PF_RB_STRIDE + lane_off;
  const f16* pH0 = Hpf + (size_t)(r0 / 32 + wr * 2 + 0) * PF_RB_STRIDE + lane_off;
  const f16* pH1 = Hpf + (size_t)(r0 / 32 + wr * 2 + 1) * PF_RB_STRIDE + lane_off;
  const f16* pWi = Wip + (size_t)(c0 / 32 + wc) * PF_RB_STRIDE + lane_off;
  const f16* pWh = Whp + (size_t)(c0 / 32 + wc) * PF_RB_STRIDE + lane_off;
#define Z16 {0,0,0,0,0,0,0,0,0,0,0,0,0,0,0,0}
  f32x16 aR0 = Z16, aR1 = Z16, aZ0 = Z16, aZ1 = Z16, aN0 = Z16, aN1 = Z16;
  f32x16 hR0 = Z16, hR1 = Z16, hZ0 = Z16, hZ1 = Z16, hN0 = Z16, hN1 = Z16;
  // phase 1: U @ Wi
#pragma unroll 2
  for (int ks = 0; ks < 24; ks++) {
    const size_t off = (size_t)ks * PF_KS_STRIDE;
    f16x8 au0 = *(const f16x8*)(pU0 + off);
    f16x8 au1 = *(const f16x8*)(pU1 + off);
    f16x8 bir = *(const f16x8*)(pWi + off);
    f16x8 biz = *(const f16x8*)(pWi + PF_GATE_STRIDE + off);
    f16x8 bin = *(const f16x8*)(pWi + 2 * PF_GATE_STRIDE + off);
    aR0 = __builtin_amdgcn_mfma_f32_32x32x16_f16(au0, bir, aR0, 0, 0, 0);
    aR1 = __builtin_amdgcn_mfma_f32_32x32x16_f16(au1, bir, aR1, 0, 0, 0);
    aZ0 = __builtin_amdgcn_mfma_f32_32x32x16_f16(au0, biz, aZ0, 0, 0, 0);
    aZ1 = __builtin_amdgcn_mfma_f32_32x32x16_f16(au1, biz, aZ1, 0, 0, 0);
    aN0 = __builtin_amdgcn_mfma_f32_32x32x16_f16(au0, bin, aN0, 0, 0, 0);
    aN1 = __builtin_amdgcn_mfma_f32_32x32x16_f16(au1, bin, aN1, 0, 0, 0);
  }
  // phase 2: H @ Wh
#pragma unroll 2
  for (int ks = 0; ks < 24; ks++) {
    const size_t off = (size_t)ks * PF_KS_STRIDE;
    f16x8 ah0 = *(const f16x8*)(pH0 + off);
    f16x8 ah1 = *(const f16x8*)(pH1 + off);
    f16x8 bhr = *(const f16x8*)(pWh + off);
    f16x8 bhz = *(const f16x8*)(pWh + PF_GATE_STRIDE + off);
    f16x8 bhn = *(const f16x8*)(pWh + 2 * PF_GATE_STRIDE + off);
    hR0 = __builtin_amdgcn_mfma_f32_32x32x16_f16(ah0, bhr, hR0, 0, 0, 0);
    hR1 = __builtin_amdgcn_mfma_f32_32x32x16_f16(ah1, bhr, hR1, 0, 0, 0);
    hZ0 = __builtin_amdgcn_mfma_f32_32x32x16_f16(ah0, bhz, hZ0, 0, 0, 0);
    hZ1 = __builtin_amdgcn_mfma_f32_32x32x16_f16(ah1, bhz, hZ1, 0, 0, 0);
    hN0 = __builtin_amdgcn_mfma_f32_32x32x16_f16(ah0, bhn, hN0, 0, 0, 0);
    hN1 = __builtin_amdgcn_mfma_f32_32x32x16_f16(ah1, bhn, hN1, 0, 0, 0);
  }
  const int col = c0 + wc * 32 + l31;  // in [0, 384)
  const float bir_ = bi[col], biz_ = bi[HID + col], bin_ = bi[2 * HID + col];
  const float bhr_ = bh[col], bhz_ = bh[HID + col], bhn_ = bh[2 * HID + col];
#pragma unroll
  for (int r = 0; r < 16; r++) {
    int crow = (r & 3) + 8 * (r >> 2) + 4 * lhi;
    {
      int row = r0 + wr * 64 + crow;
      if (row < M) {
        float rg_ = sigm(aR0[r] + hR0[r] + bir_ + bhr_);
        float zg = sigm(aZ0[r] + hZ0[r] + biz_ + bhz_);
        float ng = tanhf(aN0[r] + bin_ + rg_ * (hN0[r] + bhn_));
        float o = (1.f - zg) * ng + zg * Hsf[(size_t)row * HID + col];
        o = fmaxf(o, 0.f);
        Xo[(size_t)row * HID + col] = o;
        Xoh[pf_idx(row, col)] = (f16)o;
      }
    }
    {
      int row = r0 + wr * 64 + 32 + crow;
      if (row < M) {
        float rg_ = sigm(aR1[r] + hR1[r] + bir_ + bhr_);
        float zg = sigm(aZ1[r] + hZ1[r] + biz_ + bhz_);
        float ng = tanhf(aN1[r] + bin_ + rg_ * (hN1[r] + bhn_));
        float o = (1.f - zg) * ng + zg * Hsf[(size_t)row * HID + col];
        o = fmaxf(o, 0.f);
        Xo[(size_t)row * HID + col] = o;
        Xoh[pf_idx(row, col)] = (f16)o;
      }
    }
  }
}

// pack weight W[K][Nn] (f32, row-major) -> PF f16 over rows n (output-col major), K=384
__global__ void k_wpack(const float* __restrict__ W, f16* __restrict__ Wp, int K, int Nn)
{
  long t = (long)blockIdx.x * blockDim.x + threadIdx.x;
  if (t >= (long)K * Nn) return;
  int elem = (int)(t & 7); long c = t >> 3;
  int l31 = (int)(c & 31); long q = c >> 5;
  int lhi = (int)(q & 1); long p = q >> 1;
  int KS = K >> 4;
  int ks = (int)(p % KS); int rb = (int)(p / KS);
  int n = rb * 32 + l31, k = ks * 16 + lhi * 8 + elem;
  Wp[t] = (f16)W[(size_t)k * Nn + n];
}

// elementwise f32 row-major -> f16 PF
__global__ void k_f2h_pf(const float* __restrict__ in, f16* __restrict__ out, long total)
{
  long t = (long)blockIdx.x * blockDim.x + threadIdx.x;
  if (t >= total) return;
  int i = (int)(t / HID), c = (int)(t % HID);
  out[pf_idx(i, c)] = (f16)in[t];
}

// x1[i,c] = leaky(sum_j T1[x_idx[i,j], c] + lin1_b[c]); dual f32 + f16-PF out
__global__ void k_node_embed(const int* __restrict__ xi, const float* __restrict__ T1,
                             const float* __restrict__ b, float* __restrict__ x1,
                             f16* __restrict__ x1h, long total)
{
  long t = (long)blockIdx.x * blockDim.x + threadIdx.x;
  if (t >= total) return;
  int i = (int)(t / HID), c = (int)(t % HID);
  float v = b[c];
#pragma unroll
  for (int j = 0; j < 9; j++) v += T1[(size_t)xi[i * 9 + j] * HID + c];
  v = leaky(v);
  x1[t] = v;
  x1h[pf_idx(i, c)] = (f16)v;
}

// one 64-lane wave per row: out[r] = dot(X[r,:], v)
__global__ void k_rowdot(const float* __restrict__ X, const float* __restrict__ v,
                         float* __restrict__ out, int M)
{
  int w = (int)(((long)blockIdx.x * blockDim.x + threadIdx.x) >> 6);
  int lane = threadIdx.x & 63;
  if (w >= M) return;
  float s = 0.f;
  for (int j = lane; j < HID; j += 64) s += X[(size_t)w * HID + j] * v[j];
  for (int o = 32; o; o >>= 1) s += __shfl_down(s, o, 64);
  if (lane == 0) out[w] = s;
}

__global__ void k_rowdot2(const float* __restrict__ X, const float* __restrict__ v1,
                          const float* __restrict__ v2, float* __restrict__ o1,
                          float* __restrict__ o2, int M)
{
  int w = (int)(((long)blockIdx.x * blockDim.x + threadIdx.x) >> 6);
  int lane = threadIdx.x & 63;
  if (w >= M) return;
  float s1 = 0.f, s2 = 0.f;
  for (int j = lane; j < HID; j += 64) {
    float x = X[(size_t)w * HID + j];
    s1 += x * v1[j]; s2 += x * v2[j];
  }
  for (int o = 32; o; o >>= 1) { s1 += __shfl_down(s1, o, 64); s2 += __shfl_down(s2, o, 64); }
  if (lane == 0) { o1[w] = s1; o2[w] = s2; }
}

// GATEConv attention logits, wave per edge; m recomputed on the fly.
__global__ void k_gate_att(const float* __restrict__ P, const float* __restrict__ Te,
                           const int* __restrict__ ei, const int* __restrict__ eai,
                           const float* __restrict__ attl, const float* __restrict__ xr,
                           float* __restrict__ aE, float* __restrict__ mx, int ne)
{
  int e = (int)(((long)blockIdx.x * blockDim.x + threadIdx.x) >> 6);
  int lane = threadIdx.x & 63;
  if (e >= ne) return;
  int s = ei[e];
  int i0 = eai[e * 3], i1 = eai[e * 3 + 1], i2 = eai[e * 3 + 2];
  float acc = 0.f;
  for (int j = lane; j < HID; j += 64) {
    float m = P[(size_t)s * HID + j] + Te[(size_t)i0 * HID + j]
            + Te[(size_t)i1 * HID + j] + Te[(size_t)i2 * HID + j];
    acc += leaky(m) * attl[j];
  }
  for (int o = 32; o; o >>= 1) acc += __shfl_down(acc, o, 64);
  if (lane == 0) {
    int d = ei[NE + e];
    float a = leaky(acc + xr[d]);
    aE[e] = a;
    atomicMaxF(&mx[d], a);
  }
}

__global__ void k_gat_att(const float* __restrict__ sS, const float* __restrict__ sD,
                          const int* __restrict__ ei, float* __restrict__ aE,
                          float* __restrict__ mx, int ne)
{
  int e = (int)((long)blockIdx.x * blockDim.x + threadIdx.x);
  if (e >= ne) return;
  int s = ei[e], d = ei[NE + e];
  float a = leaky(sS[s] + sD[d]);
  aE[e] = a;
  atomicMaxF(&mx[d], a);
}

__global__ void k_mol_att(const float* __restrict__ a_node, const float* __restrict__ a_g,
                          const int* __restrict__ batch, float* __restrict__ aN,
                          float* __restrict__ mxG, int n)
{
  int i = (int)((long)blockIdx.x * blockDim.x + threadIdx.x);
  if (i >= n) return;
  int b = batch[i];
  float a = leaky(a_node[i] + a_g[b]);
  aN[i] = a;
  atomicMaxF(&mxG[b], a);
}

__global__ void k_seg_exp(float* __restrict__ a, const int* __restrict__ idx,
                          const float* __restrict__ mx, float* __restrict__ sum, int n)
{
  int t = (int)((long)blockIdx.x * blockDim.x + threadIdx.x);
  if (t >= n) return;
  int d = idx[t];
  float e = expf(a[t] - mx[d]);
  a[t] = e;
  atomicAdd(&sum[d], e);
}

__global__ void k_scatter_edge(const float* __restrict__ P, const float* __restrict__ Te,
                               const int* __restrict__ ei, const int* __restrict__ eai,
                               const float* __restrict__ aE, const float* __restrict__ sum,
                               float* __restrict__ acc, long total)
{
  long t = (long)blockIdx.x * blockDim.x + threadIdx.x;
  if (t >= total) return;
  int e = (int)(t / HID), c = (int)(t % HID);
  int s = ei[e], d = ei[NE + e];
  float m = P[(size_t)s * HID + c] + Te[(size_t)eai[e * 3] * HID + c]
          + Te[(size_t)eai[e * 3 + 1] * HID + c] + Te[(size_t)eai[e * 3 + 2] * HID + c];
  m = leaky(m);
  float w = aE[e] / (sum[d] + 1e-16f);
  atomicAdd(&acc[(size_t)d * HID + c], m * w);
}

__global__ void k_scatter_gat(const float* __restrict__ XL, const float* __restrict__ aE,
                              const float* __restrict__ sum, const int* __restrict__ ei,
                              float* __restrict__ acc, long total)
{
  long t = (long)blockIdx.x * blockDim.x + threadIdx.x;
  if (t >= total) return;
  int e = (int)(t / HID), c = (int)(t % HID);
  int s = ei[e], d = ei[NE + e];
  float w = aE[e] / (sum[d] + 1e-16f);
  atomicAdd(&acc[(size_t)d * HID + c], XL[(size_t)s * HID + c] * w);
}

__global__ void k_scatter_node(const float* __restrict__ XLm, const float* __restrict__ aN,
                               const float* __restrict__ sumG, const int* __restrict__ batch,
                               float* __restrict__ HM, long total)
{
  long t = (long)blockIdx.x * blockDim.x + threadIdx.x;
  if (t >= total) return;
  int i = (int)(t / HID), c = (int)(t % HID);
  int b = batch[i];
  float w = aN[i] / (sumG[b] + 1e-16f);
  atomicAdd(&HM[(size_t)b * HID + c], XLm[t] * w);
}

__global__ void k_scatter_sum(const float* __restrict__ X, const int* __restrict__ batch,
                              float* __restrict__ acc, long total)
{
  long t = (long)blockIdx.x * blockDim.x + threadIdx.x;
  if (t >= total) return;
  int i = (int)(t / HID), c = (int)(t % HID);
  atomicAdd(&acc[(size_t)batch[i] * HID + c], X[t]);
}

// X[t] = act(X[t] + bias[c]); act: 2=elu 3=relu; optional f16-PF dual out
__global__ void k_bias_act(float* __restrict__ X, const float* __restrict__ bias,
                           f16* __restrict__ Xh, long total, int act)
{
  long t = (long)blockIdx.x * blockDim.x + threadIdx.x;
  if (t >= total) return;
  int i = (int)(t / HID), c = (int)(t % HID);
  float v = X[t];
  if (bias) v += bias[c];
  if (act == 2) v = elu1(v);
  else if (act == 3) v = fmaxf(v, 0.f);
  X[t] = v;
  if (Xh) Xh[pf_idx(i, c)] = (f16)v;
}

extern "C" void kernel_launch(void* const* d_in, const int* in_sizes, int n_in,
                              void* d_out, int out_size, void* d_ws, size_t ws_size,
                              hipStream_t stream)
{
  const int* x_idx = (const int*)d_in[0];
  const int* edge_index = (const int*)d_in[1];
  const int* eai = (const int*)d_in[2];
  const int* batch = (const int*)d_in[3];
  const float* x_emb = (const float*)d_in[4];
  const float* e_emb = (const float*)d_in[5];
  const float* lin1_W = (const float*)d_in[6];
  const float* lin1_b = (const float*)d_in[7];
  const float* att_l = (const float*)d_in[8];
  const float* att_r = (const float*)d_in[9];
  const float* gl1_W = (const float*)d_in[10];
  const float* gl2_W = (const float*)d_in[11];
  const float* gate_b = (const float*)d_in[12];
  const float* gru1_Wi = (const float*)d_in[13];
  const float* gru1_Wh = (const float*)d_in[14];
  const float* gru1_bi = (const float*)d_in[15];
  const float* gru1_bh = (const float*)d_in[16];
  const float* gat_W = (const float*)d_in[17];
  const float* gat_as = (const float*)d_in[18];
  const float* gat_ad = (const float*)d_in[19];
  const float* gat_b = (const float*)d_in[20];
  const float* gru2_Wi = (const float*)d_in[21];
  const float* gru2_Wh = (const float*)d_in[22];
  const float* gru2_bi = (const float*)d_in[23];
  const float* gru2_bh = (const float*)d_in[24];
  const float* mol_W = (const float*)d_in[25];
  const float* mol_as = (const float*)d_in[26];
  const float* mol_ad = (const float*)d_in[27];
  const float* mol_b = (const float*)d_in[28];
  const float* mgru_Wi = (const float*)d_in[29];
  const float* mgru_Wh = (const float*)d_in[30];
  const float* mgru_bi = (const float*)d_in[31];
  const float* mgru_bh = (const float*)d_in[32];
  const float* lin2_W = (const float*)d_in[33];
  const float* lin2_b = (const float*)d_in[34];
  float* outp = (float*)d_out;

  const size_t NB = (size_t)NN * HID;
  const size_t GB = (size_t)NG * HID;
  // PF buffers: N rows pad to 944*32=30208 (256-row tiles read to 30207); G rows pad to 1280
  const size_t PFH = (size_t)944 * PF_RB_STRIDE;  // f16 elems
  const size_t PFG = (size_t)40 * PF_RB_STRIDE;

  float* ws = (float*)d_ws;
  size_t off = 0;
  auto alloc = [&](size_t n) { float* p = ws + off; off += n; return p; };
  auto alloch = [&](size_t n) { f16* p = (f16*)(ws + off); off += (n + 1) / 2; return p; };
  float* A    = alloc(NB);
  float* B    = alloc(NB);
  float* C    = alloc(NB);
  f16* H1 = alloch(PFH);
  f16* H2 = alloch(PFH);
  f16* H3 = alloch(PFH);
  f16* W1p   = alloch((size_t)HID * HID);
  f16* W2p   = alloch((size_t)HID * HID);
  f16* Wgatp = alloch((size_t)HID * HID);
  f16* Wmolp = alloch((size_t)HID * HID);
  f16* Wg1ip = alloch((size_t)3 * HID * HID);
  f16* Wg1hp = alloch((size_t)3 * HID * HID);
  f16* Wg2ip = alloch((size_t)3 * HID * HID);
  f16* Wg2hp = alloch((size_t)3 * HID * HID);
  f16* Wmgip = alloch((size_t)3 * HID * HID);
  f16* Wmghp = alloch((size_t)3 * HID * HID);
  f16* Wl2p  = alloch((size_t)HID * OUTD);
  f16* OUTaPF = alloch(PFG);
  f16* OUTbPF = alloch(PFG);
  f16* HMp    = alloch(PFG);
  float* T1   = alloc((size_t)178 * HID);
  float* Te   = alloc((size_t)18 * HID);
  float* xr   = alloc(NN);
  float* sS   = alloc(NN);
  float* sD   = alloc(NN);
  float* mxN  = alloc(NN);
  float* sumN = alloc(NN);
  float* aN   = alloc(NN);
  float* a_node = alloc(NN);
  float* aE   = alloc(NE);
  float* mxG  = alloc(NG);
  float* sumG = alloc(NG);
  float* a_g  = alloc(NG);
  float* OUTa = alloc(GB);
  float* OUTb = alloc(GB);
  float* GM   = alloc(GB);
  float* HM   = alloc(GB);
  (void)n_in; (void)in_sizes; (void)out_size;
  if (ws_size < off * sizeof(float)) return;  // fail loud, not with a GPU fault

  const int* dstArr = edge_index + NE;
  dim3 blk(256);
  auto g1 = [](long n) { return dim3((unsigned)((n + 255) / 256)); };
  auto gw = [](long waves) { return dim3((unsigned)((waves * 64 + 255) / 256)); };
  const long NBt = (long)NB, EBt = (long)NE * HID, GBt = (long)GB;
  // 1D XCD-grouped grids for the MFMA kernels (v2 tiles: hgemm 256x128, gru 128x64)
  const int MtH = (NN + 255) / 256;                       // 118
  const dim3 gH((unsigned)(8 * 3 * ((MtH + 7) / 8)));     // 360
  const int MtR = (NN + 127) / 128;                       // 235
  const dim3 gR((unsigned)(8 * 6 * ((MtR + 7) / 8)));     // 1440
  const int MtGH = (NG + 255) / 256;                      // 5
  const dim3 gGM((unsigned)(8 * 3 * ((MtGH + 7) / 8)));   // 24   (Nn=HID)
  const dim3 gF((unsigned)(8 * 6 * ((MtGH + 7) / 8)));    // 48   (Nn=OUTD)
  const int MtGR = (NG + 127) / 128;                      // 10
  const dim3 gRG((unsigned)(8 * 6 * ((MtGR + 7) / 8)));   // 96

  // ---- weight prep: f16 PF-packed copies ----
  hipLaunchKernelGGL(k_wpack, g1((long)HID * HID), blk, 0, stream, gl1_W, W1p, HID, HID);
  hipLaunchKernelGGL(k_wpack, g1((long)HID * HID), blk, 0, stream, gl2_W, W2p, HID, HID);
  hipLaunchKernelGGL(k_wpack, g1((long)HID * HID), blk, 0, stream, gat_W, Wgatp, HID, HID);
  hipLaunchKernelGGL(k_wpack, g1((long)HID * HID), blk, 0, stream, mol_W, Wmolp, HID, HID);
  hipLaunchKernelGGL(k_wpack, g1((long)3 * HID * HID), blk, 0, stream, gru1_Wi, Wg1ip, HID, 3 * HID);
  hipLaunchKernelGGL(k_wpack, g1((long)3 * HID * HID), blk, 0, stream, gru1_Wh, Wg1hp, HID, 3 * HID);
  hipLaunchKernelGGL(k_wpack, g1((long)3 * HID * HID), blk, 0, stream, gru2_Wi, Wg2ip, HID, 3 * HID);
  hipLaunchKernelGGL(k_wpack, g1((long)3 * HID * HID), blk, 0, stream, gru2_Wh, Wg2hp, HID, 3 * HID);
  hipLaunchKernelGGL(k_wpack, g1((long)3 * HID * HID), blk, 0, stream, mgru_Wi, Wmgip, HID, 3 * HID);
  hipLaunchKernelGGL(k_wpack, g1((long)3 * HID * HID), blk, 0, stream, mgru_Wh, Wmghp, HID, 3 * HID);
  hipLaunchKernelGGL(k_wpack, g1((long)HID * OUTD), blk, 0, stream, lin2_W, Wl2p, HID, OUTD);

  // ---- tables ----
  hipLaunchKernelGGL(k_gemm, dim3(HID / 64, 3), blk, 0, stream,
                     x_emb, lin1_W, nullptr, T1, 178, HID, EMB, 0);
  hipLaunchKernelGGL(k_gemm, dim3(HID / 64, 1), blk, 0, stream,
                     e_emb, gl1_W + (size_t)HID * HID, nullptr, Te, 18, HID, EMB, 0);

  // ---- x1 ----
  hipLaunchKernelGGL(k_node_embed, g1(NBt), blk, 0, stream, x_idx, T1, lin1_b, A, H1, NBt);

  // ---- GATEConv ----
  hipLaunchKernelGGL(k_hgemm, gH, blk, 0, stream, H1, W1p, nullptr, B, (f16*)nullptr, NN, HID, 0); // P
  hipLaunchKernelGGL(k_rowdot, gw(NN), blk, 0, stream, A, att_r, xr, NN);
  hipMemsetAsync(mxN, 0xFF, NN * sizeof(float), stream);
  hipLaunchKernelGGL(k_gate_att, gw(NE), blk, 0, stream, B, Te, edge_index, eai, att_l, xr, aE, mxN, NE);
  hipMemsetAsync(sumN, 0, NN * sizeof(float), stream);
  hipLaunchKernelGGL(k_seg_exp, g1(NE), blk, 0, stream, aE, dstArr, mxN, sumN, NE);
  hipMemsetAsync(C, 0, NB * sizeof(float), stream);
  hipLaunchKernelGGL(k_scatter_edge, g1(EBt), blk, 0, stream, B, Te, edge_index, eai, aE, sumN, C, EBt);
  hipLaunchKernelGGL(k_f2h_pf, g1(NBt), blk, 0, stream, C, H2, NBt);
  hipLaunchKernelGGL(k_hgemm, gH, blk, 0, stream, H2, W2p, gate_b, (float*)nullptr, H3, NN, HID, 2); // elu(h)
  // GRU1: x2 -> C (f32) + H2 (f16 PF)
  hipLaunchKernelGGL(k_gru_hgemm, gR, blk, 0, stream, H3, H1, A, Wg1ip, Wg1hp, gru1_bi, gru1_bh, C, H2, NN);

  // ---- GAT layer ----
  hipLaunchKernelGGL(k_hgemm, gH, blk, 0, stream, H2, Wgatp, nullptr, B, (f16*)nullptr, NN, HID, 0); // XL
  hipLaunchKernelGGL(k_rowdot2, gw(NN), blk, 0, stream, B, gat_as, gat_ad, sS, sD, NN);
  hipMemsetAsync(mxN, 0xFF, NN * sizeof(float), stream);
  hipLaunchKernelGGL(k_gat_att, g1(NE), blk, 0, stream, sS, sD, edge_index, aE, mxN, NE);
  hipMemsetAsync(sumN, 0, NN * sizeof(float), stream);
  hipLaunchKernelGGL(k_seg_exp, g1(NE), blk, 0, stream, aE, dstArr, mxN, sumN, NE);
  hipMemsetAsync(A, 0, NB * sizeof(float), stream);
  hipLaunchKernelGGL(k_scatter_gat, g1(EBt), blk, 0, stream, B, aE, sumN, edge_index, A, EBt);
  hipLaunchKernelGGL(k_bias_act, g1(NBt), blk, 0, stream, A, gat_b, H1, NBt, 2); // A=elu, H1=PF
  // GRU2: x3 -> B (f32) + H3 (f16 PF)
  hipLaunchKernelGGL(k_gru_hgemm, gR, blk, 0, stream, H1, H2, C, Wg2ip, Wg2hp, gru2_bi, gru2_bh, B, H3, NN);

  // ---- molecule readout ----
  hipMemsetAsync(OUTa, 0, GB * sizeof(float), stream);
  hipLaunchKernelGGL(k_scatter_sum, g1(NBt), blk, 0, stream, B, batch, OUTa, NBt);
  hipLaunchKernelGGL(k_bias_act, g1(GBt), blk, 0, stream, OUTa, (const float*)nullptr, OUTaPF, GBt, 3);
  hipLaunchKernelGGL(k_hgemm, gH, blk, 0, stream, H3, Wmolp, nullptr, A, (f16*)nullptr, NN, HID, 0); // XLm
  hipLaunchKernelGGL(k_rowdot, gw(NN), blk, 0, stream, A, mol_as, a_node, NN);

  float* cur = OUTa;   f16* curPF = OUTaPF;
  float* nxt = OUTb;   f16* nxtPF = OUTbPF;
  for (int t = 0; t < 3; t++) {
    hipLaunchKernelGGL(k_hgemm, gGM, blk, 0, stream, curPF, Wmolp, nullptr, GM, (f16*)nullptr, NG, HID, 0);
    hipLaunchKernelGGL(k_rowdot, gw(NG), blk, 0, stream, GM, mol_ad, a_g, NG);
    hipMemsetAsync(mxG, 0xFF, NG * sizeof(float), stream);
    hipLaunchKernelGGL(k_mol_att, g1(NN), blk, 0, stream, a_node, a_g, batch, aN, mxG, NN);
    hipMemsetAsync(sumG, 0, NG * sizeof(float), stream);
    hipLaunchKernelGGL(k_seg_exp, g1(NN), blk, 0, stream, aN, batch, mxG, sumG, NN);
    hipMemsetAsync(HM, 0, GB * sizeof(float), stream);
    hipLaunchKernelGGL(k_scatter_node, g1(NBt), blk, 0, stream, A, aN, sumG, batch, HM, NBt);
    hipLaunchKernelGGL(k_bias_act, g1(GBt), blk, 0, stream, HM, mol_b, HMp, GBt, 2);
    hipLaunchKernelGGL(k_gru_hgemm, gRG, blk, 0, stream, HMp, curPF, cur,
                       Wmgip, Wmghp, mgru_bi, mgru_bh, nxt, nxtPF, NG);
    float* tf = cur; cur = nxt; nxt = tf;
    f16* th = curPF; curPF = nxtPF; nxtPF = th;
  }

  // ---- final projection: out = cur @ lin2_W + lin2_b ----
  hipLaunchKernelGGL(k_hgemm, gF, blk, 0, stream, curPF, Wl2p, lin2_b, outp, (f16*)nullptr, NG, OUTD, 0);
}

// Round 8
// 1197.137 us; speedup vs baseline: 1.3880x; 1.3880x over previous
//
#include <hip/hip_runtime.h>
#include <cstdint>
#include <cstddef>

#define NN 30000
#define NE 60000
#define NG 1200
#define HID 384
#define EMB 768
#define OUTD 768
#define NEGS 0.01f

typedef _Float16 f16;
typedef _Float16 f16x8 __attribute__((ext_vector_type(8)));
typedef float f32x16 __attribute__((ext_vector_type(16)));

static __device__ __forceinline__ float leaky(float x){ return x > 0.f ? x : NEGS * x; }
static __device__ __forceinline__ float elu1(float x){ return x > 0.f ? x : (expf(x) - 1.f); }
static __device__ __forceinline__ float sigm(float x){ return 1.f / (1.f + expf(-x)); }

static __device__ __forceinline__ void atomicMaxF(float* a, float v){
  if (v >= 0.f) atomicMax((int*)a, __float_as_int(v));
  else atomicMin((unsigned int*)a, __float_as_uint(v));
}

// ---- fragment-packed (PF) layout for K=384 operands of mfma_32x32x16 ----
// chunk(rb,ks,lhi,l31) holds X[rb*32+l31][ks*16+lhi*8 .. +8]; wave reads 1KB contiguous.
static __device__ __forceinline__ size_t pf_idx(int row, int col){
  return (((((size_t)(row >> 5)) * 24 + (col >> 4)) * 2 + ((col >> 3) & 1)) * 32
          + (row & 31)) * 8 + (col & 7);
}
#define PF_RB_STRIDE 12288   // 24 ks * 64 lanes * 8 elems
#define PF_KS_STRIDE 512     // 64 lanes * 8 elems
#define PF_GATE_STRIDE 147456  // 12 rb * PF_RB_STRIDE  (= HID*HID)

// ---------------- f32 tiled GEMM (tables only) ----------------
__global__ __launch_bounds__(256) void k_gemm(
    const float* __restrict__ A, const float* __restrict__ B,
    const float* __restrict__ bias, float* __restrict__ C,
    int M, int N, int K, int act)
{
  __shared__ float As[16][65];
  __shared__ float Bs[16][65];
  const int tid = threadIdx.x;
  const int tx = tid & 15, ty = tid >> 4;
  const int row0 = blockIdx.y * 64, col0 = blockIdx.x * 64;
  const int ar = tid >> 2, ak = (tid & 3) << 2;
  const int bk = tid >> 4, bc = (tid & 15) << 2;
  float acc[4][4] = {};
  for (int k0 = 0; k0 < K; k0 += 16) {
    float4 av = make_float4(0.f, 0.f, 0.f, 0.f);
    if (row0 + ar < M)
      av = *(const float4*)(A + (size_t)(row0 + ar) * K + k0 + ak);
    As[ak + 0][ar] = av.x; As[ak + 1][ar] = av.y;
    As[ak + 2][ar] = av.z; As[ak + 3][ar] = av.w;
    float4 bv = *(const float4*)(B + (size_t)(k0 + bk) * N + col0 + bc);
    Bs[bk][bc + 0] = bv.x; Bs[bk][bc + 1] = bv.y;
    Bs[bk][bc + 2] = bv.z; Bs[bk][bc + 3] = bv.w;
    __syncthreads();
#pragma unroll
    for (int kk = 0; kk < 16; kk++) {
      float a[4], b[4];
#pragma unroll
      for (int i = 0; i < 4; i++) a[i] = As[kk][(ty << 2) + i];
#pragma unroll
      for (int j = 0; j < 4; j++) b[j] = Bs[kk][(tx << 2) + j];
#pragma unroll
      for (int i = 0; i < 4; i++)
#pragma unroll
        for (int j = 0; j < 4; j++)
          acc[i][j] = fmaf(a[i], b[j], acc[i][j]);
    }
    __syncthreads();
  }
#pragma unroll
  for (int i = 0; i < 4; i++) {
    int r = row0 + (ty << 2) + i;
    if (r >= M) continue;
#pragma unroll
    for (int j = 0; j < 4; j++) {
      int c = col0 + (tx << 2) + j;
      float v = acc[i][j];
      if (bias) v += bias[c];
      if (act == 1) v = leaky(v);
      else if (act == 2) v = elu1(v);
      else if (act == 3) v = fmaxf(v, 0.f);
      C[(size_t)r * N + c] = v;
    }
  }
}

// ------------- MFMA f16 GEMM (v1 tile + register prefetch), PF operands, no LDS -------------
// C = act(A[M,384] @ B[Nn,384]^T + bias). Block 128x128, 4 waves 2x2; wave 64x64, 4 accs.
__global__ __launch_bounds__(256) void k_hgemm(
    const f16* __restrict__ Apf, const f16* __restrict__ Bpf,
    const float* __restrict__ bias, float* __restrict__ Cf, f16* __restrict__ Ch,
    int M, int Nn, int act)
{
  const int nct = Nn >> 7;
  const int id = blockIdx.x;
  const int lane8 = id & 7, chunk = id >> 3;
  const int ct = chunk % nct, rg = chunk / nct;
  const int rt = rg * 8 + lane8;
  const int Mt = (M + 127) >> 7;
  if (rt >= Mt) return;
  const int r0 = rt * 128, n0 = ct * 128;
  const int tid = threadIdx.x;
  const int wid = tid >> 6, lane = tid & 63;
  const int wr = wid >> 1, wc = wid & 1;
  const int l31 = lane & 31, lhi = lane >> 5;
  const size_t lane_off = (size_t)(lhi * 32 + l31) * 8;
  const f16* pA[2]; const f16* pB[2];
#pragma unroll
  for (int i = 0; i < 2; i++) {
    pA[i] = Apf + (size_t)(r0 / 32 + wr * 2 + i) * PF_RB_STRIDE + lane_off;
    pB[i] = Bpf + (size_t)(n0 / 32 + wc * 2 + i) * PF_RB_STRIDE + lane_off;
  }
  f32x16 acc[2][2];
#pragma unroll
  for (int i = 0; i < 2; i++)
#pragma unroll
    for (int j = 0; j < 2; j++)
#pragma unroll
      for (int r = 0; r < 16; r++) acc[i][j][r] = 0.f;
  f16x8 af[2], bf[2], naf[2], nbf[2];
#pragma unroll
  for (int i = 0; i < 2; i++) { af[i] = *(const f16x8*)(pA[i]); bf[i] = *(const f16x8*)(pB[i]); }
#pragma unroll 4
  for (int ks = 0; ks < 24; ks++) {
    const size_t noff = (size_t)(ks < 23 ? ks + 1 : 23) * PF_KS_STRIDE;
#pragma unroll
    for (int i = 0; i < 2; i++) { naf[i] = *(const f16x8*)(pA[i] + noff); nbf[i] = *(const f16x8*)(pB[i] + noff); }
#pragma unroll
    for (int i = 0; i < 2; i++)
#pragma unroll
      for (int j = 0; j < 2; j++)
        acc[i][j] = __builtin_amdgcn_mfma_f32_32x32x16_f16(af[i], bf[j], acc[i][j], 0, 0, 0);
#pragma unroll
    for (int i = 0; i < 2; i++) { af[i] = naf[i]; bf[i] = nbf[i]; }
  }
#pragma unroll
  for (int i = 0; i < 2; i++)
#pragma unroll
    for (int j = 0; j < 2; j++) {
      int col = n0 + wc * 64 + j * 32 + l31;
      float bv = bias ? bias[col] : 0.f;
#pragma unroll
      for (int r = 0; r < 16; r++) {
        int row = r0 + wr * 64 + i * 32 + (r & 3) + 8 * (r >> 2) + 4 * lhi;
        if (row < M) {
          float v = acc[i][j][r] + bv;
          if (act == 1) v = leaky(v);
          else if (act == 2) v = elu1(v);
          else if (act == 3) v = fmaxf(v, 0.f);
          if (Cf) Cf[(size_t)row * Nn + col] = v;
          if (Ch) Ch[pf_idx(row, col)] = (f16)v;  // only used when Nn==HID
        }
      }
    }
}

// ------------- MFMA f16 fused GRU v3: 4 accs + register prefetch, PF h-state -------------
// r/z accumulate U@Wi and H@Wh into the SAME acc (sum needed anyway); n keeps aN,hN split.
// h-state read from Hpf (f16 PF) in epilogue; f32 out optional (Xo may be null).
__global__ __launch_bounds__(256) void k_gru_hgemm(
    const f16* __restrict__ Upf, const f16* __restrict__ Hpf,
    const f16* __restrict__ Wip, const f16* __restrict__ Whp,
    const float* __restrict__ bi, const float* __restrict__ bh,
    float* __restrict__ Xo, f16* __restrict__ Xoh, int M)
{
  const int id = blockIdx.x;
  const int lane8 = id & 7, chunk = id >> 3;
  const int ct = chunk % 6, rg = chunk / 6;
  const int rt = rg * 8 + lane8;
  const int Mt = (M + 63) >> 6;
  if (rt >= Mt) return;
  const int r0 = rt * 64, c0 = ct * 64;
  const int tid = threadIdx.x;
  const int wid = tid >> 6, lane = tid & 63;
  const int wr = wid >> 1, wc = wid & 1;
  const int l31 = lane & 31, lhi = lane >> 5;
  const size_t lane_off = (size_t)(lhi * 32 + l31) * 8;
  const f16* pU  = Upf + (size_t)(r0 / 32 + wr) * PF_RB_STRIDE + lane_off;
  const f16* pH  = Hpf + (size_t)(r0 / 32 + wr) * PF_RB_STRIDE + lane_off;
  const f16* pWi = Wip + (size_t)(c0 / 32 + wc) * PF_RB_STRIDE + lane_off;
  const f16* pWh = Whp + (size_t)(c0 / 32 + wc) * PF_RB_STRIDE + lane_off;
#define Z16 {0,0,0,0,0,0,0,0,0,0,0,0,0,0,0,0}
  f32x16 accR = Z16, accZ = Z16, aN = Z16, hN = Z16;
  f16x8 au, ah, bir, biz, bin, bhr, bhz, bhn;
  f16x8 nau, nah, nbir, nbiz, nbin, nbhr, nbhz, nbhn;
  au  = *(const f16x8*)(pU);
  ah  = *(const f16x8*)(pH);
  bir = *(const f16x8*)(pWi);
  biz = *(const f16x8*)(pWi + PF_GATE_STRIDE);
  bin = *(const f16x8*)(pWi + 2 * PF_GATE_STRIDE);
  bhr = *(const f16x8*)(pWh);
  bhz = *(const f16x8*)(pWh + PF_GATE_STRIDE);
  bhn = *(const f16x8*)(pWh + 2 * PF_GATE_STRIDE);
#pragma unroll 4
  for (int ks = 0; ks < 24; ks++) {
    const size_t noff = (size_t)(ks < 23 ? ks + 1 : 23) * PF_KS_STRIDE;
    nau  = *(const f16x8*)(pU + noff);
    nah  = *(const f16x8*)(pH + noff);
    nbir = *(const f16x8*)(pWi + noff);
    nbiz = *(const f16x8*)(pWi + PF_GATE_STRIDE + noff);
    nbin = *(const f16x8*)(pWi + 2 * PF_GATE_STRIDE + noff);
    nbhr = *(const f16x8*)(pWh + noff);
    nbhz = *(const f16x8*)(pWh + PF_GATE_STRIDE + noff);
    nbhn = *(const f16x8*)(pWh + 2 * PF_GATE_STRIDE + noff);
    accR = __builtin_amdgcn_mfma_f32_32x32x16_f16(au, bir, accR, 0, 0, 0);
    accR = __builtin_amdgcn_mfma_f32_32x32x16_f16(ah, bhr, accR, 0, 0, 0);
    accZ = __builtin_amdgcn_mfma_f32_32x32x16_f16(au, biz, accZ, 0, 0, 0);
    accZ = __builtin_amdgcn_mfma_f32_32x32x16_f16(ah, bhz, accZ, 0, 0, 0);
    aN   = __builtin_amdgcn_mfma_f32_32x32x16_f16(au, bin, aN, 0, 0, 0);
    hN   = __builtin_amdgcn_mfma_f32_32x32x16_f16(ah, bhn, hN, 0, 0, 0);
    au = nau; ah = nah; bir = nbir; biz = nbiz; bin = nbin;
    bhr = nbhr; bhz = nbhz; bhn = nbhn;
  }
  const int col = c0 + wc * 32 + l31;  // in [0, 384)
  const float brz = bi[col] + bh[col];
  const float bzz = bi[HID + col] + bh[HID + col];
  const float bin_ = bi[2 * HID + col];
  const float bhn_ = bh[2 * HID + col];
#pragma unroll
  for (int r = 0; r < 16; r++) {
    int row = r0 + wr * 32 + (r & 3) + 8 * (r >> 2) + 4 * lhi;
    if (row < M) {
      float rg_ = sigm(accR[r] + brz);
      float zg  = sigm(accZ[r] + bzz);
      float ng  = tanhf(aN[r] + bin_ + rg_ * (hN[r] + bhn_));
      float hp  = (float)Hpf[pf_idx(row, col)];
      float o = (1.f - zg) * ng + zg * hp;
      o = fmaxf(o, 0.f);
      if (Xo) Xo[(size_t)row * HID + col] = o;
      Xoh[pf_idx(row, col)] = (f16)o;
    }
  }
}

// pack weight W[K][Nn] (f32, row-major) -> PF f16 over rows n (output-col major), K=384
__global__ void k_wpack(const float* __restrict__ W, f16* __restrict__ Wp, int K, int Nn)
{
  long t = (long)blockIdx.x * blockDim.x + threadIdx.x;
  if (t >= (long)K * Nn) return;
  int elem = (int)(t & 7); long c = t >> 3;
  int l31 = (int)(c & 31); long q = c >> 5;
  int lhi = (int)(q & 1); long p = q >> 1;
  int KS = K >> 4;
  int ks = (int)(p % KS); int rb = (int)(p / KS);
  int n = rb * 32 + l31, k = ks * 16 + lhi * 8 + elem;
  Wp[t] = (f16)W[(size_t)k * Nn + n];
}

// elementwise f32 row-major -> f16 PF
__global__ void k_f2h_pf(const float* __restrict__ in, f16* __restrict__ out, long total)
{
  long t = (long)blockIdx.x * blockDim.x + threadIdx.x;
  if (t >= total) return;
  int i = (int)(t / HID), c = (int)(t % HID);
  out[pf_idx(i, c)] = (f16)in[t];
}

// x1[i,c] = leaky(sum_j T1[x_idx[i,j], c] + lin1_b[c]); dual f32 + f16-PF out
__global__ void k_node_embed(const int* __restrict__ xi, const float* __restrict__ T1,
                             const float* __restrict__ b, float* __restrict__ x1,
                             f16* __restrict__ x1h, long total)
{
  long t = (long)blockIdx.x * blockDim.x + threadIdx.x;
  if (t >= total) return;
  int i = (int)(t / HID), c = (int)(t % HID);
  float v = b[c];
#pragma unroll
  for (int j = 0; j < 9; j++) v += T1[(size_t)xi[i * 9 + j] * HID + c];
  v = leaky(v);
  x1[t] = v;
  x1h[pf_idx(i, c)] = (f16)v;
}

// one 64-lane wave per row: out[r] = dot(X[r,:], v)
__global__ void k_rowdot(const float* __restrict__ X, const float* __restrict__ v,
                         float* __restrict__ out, int M)
{
  int w = (int)(((long)blockIdx.x * blockDim.x + threadIdx.x) >> 6);
  int lane = threadIdx.x & 63;
  if (w >= M) return;
  float s = 0.f;
  for (int j = lane; j < HID; j += 64) s += X[(size_t)w * HID + j] * v[j];
  for (int o = 32; o; o >>= 1) s += __shfl_down(s, o, 64);
  if (lane == 0) out[w] = s;
}

__global__ void k_rowdot2(const float* __restrict__ X, const float* __restrict__ v1,
                          const float* __restrict__ v2, float* __restrict__ o1,
                          float* __restrict__ o2, int M)
{
  int w = (int)(((long)blockIdx.x * blockDim.x + threadIdx.x) >> 6);
  int lane = threadIdx.x & 63;
  if (w >= M) return;
  float s1 = 0.f, s2 = 0.f;
  for (int j = lane; j < HID; j += 64) {
    float x = X[(size_t)w * HID + j];
    s1 += x * v1[j]; s2 += x * v2[j];
  }
  for (int o = 32; o; o >>= 1) { s1 += __shfl_down(s1, o, 64); s2 += __shfl_down(s2, o, 64); }
  if (lane == 0) { o1[w] = s1; o2[w] = s2; }
}

// GATEConv attention logits, wave per edge; m recomputed on the fly.
__global__ void k_gate_att(const float* __restrict__ P, const float* __restrict__ Te,
                           const int* __restrict__ ei, const int* __restrict__ eai,
                           const float* __restrict__ attl, const float* __restrict__ xr,
                           float* __restrict__ aE, float* __restrict__ mx, int ne)
{
  int e = (int)(((long)blockIdx.x * blockDim.x + threadIdx.x) >> 6);
  int lane = threadIdx.x & 63;
  if (e >= ne) return;
  int s = ei[e];
  int i0 = eai[e * 3], i1 = eai[e * 3 + 1], i2 = eai[e * 3 + 2];
  float acc = 0.f;
  for (int j = lane; j < HID; j += 64) {
    float m = P[(size_t)s * HID + j] + Te[(size_t)i0 * HID + j]
            + Te[(size_t)i1 * HID + j] + Te[(size_t)i2 * HID + j];
    acc += leaky(m) * attl[j];
  }
  for (int o = 32; o; o >>= 1) acc += __shfl_down(acc, o, 64);
  if (lane == 0) {
    int d = ei[NE + e];
    float a = leaky(acc + xr[d]);
    aE[e] = a;
    atomicMaxF(&mx[d], a);
  }
}

__global__ void k_gat_att(const float* __restrict__ sS, const float* __restrict__ sD,
                          const int* __restrict__ ei, float* __restrict__ aE,
                          float* __restrict__ mx, int ne)
{
  int e = (int)((long)blockIdx.x * blockDim.x + threadIdx.x);
  if (e >= ne) return;
  int s = ei[e], d = ei[NE + e];
  float a = leaky(sS[s] + sD[d]);
  aE[e] = a;
  atomicMaxF(&mx[d], a);
}

__global__ void k_mol_att(const float* __restrict__ a_node, const float* __restrict__ a_g,
                          const int* __restrict__ batch, float* __restrict__ aN,
                          float* __restrict__ mxG, int n)
{
  int i = (int)((long)blockIdx.x * blockDim.x + threadIdx.x);
  if (i >= n) return;
  int b = batch[i];
  float a = leaky(a_node[i] + a_g[b]);
  aN[i] = a;
  atomicMaxF(&mxG[b], a);
}

__global__ void k_seg_exp(float* __restrict__ a, const int* __restrict__ idx,
                          const float* __restrict__ mx, float* __restrict__ sum, int n)
{
  int t = (int)((long)blockIdx.x * blockDim.x + threadIdx.x);
  if (t >= n) return;
  int d = idx[t];
  float e = expf(a[t] - mx[d]);
  a[t] = e;
  atomicAdd(&sum[d], e);
}

__global__ void k_scatter_edge(const float* __restrict__ P, const float* __restrict__ Te,
                               const int* __restrict__ ei, const int* __restrict__ eai,
                               const float* __restrict__ aE, const float* __restrict__ sum,
                               float* __restrict__ acc, long total)
{
  long t = (long)blockIdx.x * blockDim.x + threadIdx.x;
  if (t >= total) return;
  int e = (int)(t / HID), c = (int)(t % HID);
  int s = ei[e], d = ei[NE + e];
  float m = P[(size_t)s * HID + c] + Te[(size_t)eai[e * 3] * HID + c]
          + Te[(size_t)eai[e * 3 + 1] * HID + c] + Te[(size_t)eai[e * 3 + 2] * HID + c];
  m = leaky(m);
  float w = aE[e] / (sum[d] + 1e-16f);
  atomicAdd(&acc[(size_t)d * HID + c], m * w);
}

__global__ void k_scatter_gat(const float* __restrict__ XL, const float* __restrict__ aE,
                              const float* __restrict__ sum, const int* __restrict__ ei,
                              float* __restrict__ acc, long total)
{
  long t = (long)blockIdx.x * blockDim.x + threadIdx.x;
  if (t >= total) return;
  int e = (int)(t / HID), c = (int)(t % HID);
  int s = ei[e], d = ei[NE + e];
  float w = aE[e] / (sum[d] + 1e-16f);
  atomicAdd(&acc[(size_t)d * HID + c], XL[(size_t)s * HID + c] * w);
}

__global__ void k_scatter_node(const float* __restrict__ XLm, const float* __restrict__ aN,
                               const float* __restrict__ sumG, const int* __restrict__ batch,
                               float* __restrict__ HM, long total)
{
  long t = (long)blockIdx.x * blockDim.x + threadIdx.x;
  if (t >= total) return;
  int i = (int)(t / HID), c = (int)(t % HID);
  int b = batch[i];
  float w = aN[i] / (sumG[b] + 1e-16f);
  atomicAdd(&HM[(size_t)b * HID + c], XLm[t] * w);
}

__global__ void k_scatter_sum(const float* __restrict__ X, const int* __restrict__ batch,
                              float* __restrict__ acc, long total)
{
  long t = (long)blockIdx.x * blockDim.x + threadIdx.x;
  if (t >= total) return;
  int i = (int)(t / HID), c = (int)(t % HID);
  atomicAdd(&acc[(size_t)batch[i] * HID + c], X[t]);
}

// X[t] = act(X[t] + bias[c]); act: 2=elu 3=relu; optional f16-PF dual out
__global__ void k_bias_act(float* __restrict__ X, const float* __restrict__ bias,
                           f16* __restrict__ Xh, long total, int act)
{
  long t = (long)blockIdx.x * blockDim.x + threadIdx.x;
  if (t >= total) return;
  int i = (int)(t / HID), c = (int)(t % HID);
  float v = X[t];
  if (bias) v += bias[c];
  if (act == 2) v = elu1(v);
  else if (act == 3) v = fmaxf(v, 0.f);
  X[t] = v;
  if (Xh) Xh[pf_idx(i, c)] = (f16)v;
}

extern "C" void kernel_launch(void* const* d_in, const int* in_sizes, int n_in,
                              void* d_out, int out_size, void* d_ws, size_t ws_size,
                              hipStream_t stream)
{
  const int* x_idx = (const int*)d_in[0];
  const int* edge_index = (const int*)d_in[1];
  const int* eai = (const int*)d_in[2];
  const int* batch = (const int*)d_in[3];
  const float* x_emb = (const float*)d_in[4];
  const float* e_emb = (const float*)d_in[5];
  const float* lin1_W = (const float*)d_in[6];
  const float* lin1_b = (const float*)d_in[7];
  const float* att_l = (const float*)d_in[8];
  const float* att_r = (const float*)d_in[9];
  const float* gl1_W = (const float*)d_in[10];
  const float* gl2_W = (const float*)d_in[11];
  const float* gate_b = (const float*)d_in[12];
  const float* gru1_Wi = (const float*)d_in[13];
  const float* gru1_Wh = (const float*)d_in[14];
  const float* gru1_bi = (const float*)d_in[15];
  const float* gru1_bh = (const float*)d_in[16];
  const float* gat_W = (const float*)d_in[17];
  const float* gat_as = (const float*)d_in[18];
  const float* gat_ad = (const float*)d_in[19];
  const float* gat_b = (const float*)d_in[20];
  const float* gru2_Wi = (const float*)d_in[21];
  const float* gru2_Wh = (const float*)d_in[22];
  const float* gru2_bi = (const float*)d_in[23];
  const float* gru2_bh = (const float*)d_in[24];
  const float* mol_W = (const float*)d_in[25];
  const float* mol_as = (const float*)d_in[26];
  const float* mol_ad = (const float*)d_in[27];
  const float* mol_b = (const float*)d_in[28];
  const float* mgru_Wi = (const float*)d_in[29];
  const float* mgru_Wh = (const float*)d_in[30];
  const float* mgru_bi = (const float*)d_in[31];
  const float* mgru_bh = (const float*)d_in[32];
  const float* lin2_W = (const float*)d_in[33];
  const float* lin2_b = (const float*)d_in[34];
  float* outp = (float*)d_out;

  const size_t NB = (size_t)NN * HID;
  const size_t GB = (size_t)NG * HID;
  // PF buffers: N rows pad to 940*32=30080 (128-row tiles read to 30079); G rows pad to 1280
  const size_t PFH = (size_t)940 * PF_RB_STRIDE;  // f16 elems
  const size_t PFG = (size_t)40 * PF_RB_STRIDE;

  float* ws = (float*)d_ws;
  size_t off = 0;
  auto alloc = [&](size_t n) { float* p = ws + off; off += n; return p; };
  auto alloch = [&](size_t n) { f16* p = (f16*)(ws + off); off += (n + 1) / 2; return p; };
  float* A    = alloc(NB);
  float* B    = alloc(NB);
  float* C    = alloc(NB);
  f16* H1 = alloch(PFH);
  f16* H2 = alloch(PFH);
  f16* H3 = alloch(PFH);
  f16* W1p   = alloch((size_t)HID * HID);
  f16* W2p   = alloch((size_t)HID * HID);
  f16* Wgatp = alloch((size_t)HID * HID);
  f16* Wmolp = alloch((size_t)HID * HID);
  f16* Wg1ip = alloch((size_t)3 * HID * HID);
  f16* Wg1hp = alloch((size_t)3 * HID * HID);
  f16* Wg2ip = alloch((size_t)3 * HID * HID);
  f16* Wg2hp = alloch((size_t)3 * HID * HID);
  f16* Wmgip = alloch((size_t)3 * HID * HID);
  f16* Wmghp = alloch((size_t)3 * HID * HID);
  f16* Wl2p  = alloch((size_t)HID * OUTD);
  f16* OUTaPF = alloch(PFG);
  f16* OUTbPF = alloch(PFG);
  f16* HMp    = alloch(PFG);
  float* T1   = alloc((size_t)178 * HID);
  float* Te   = alloc((size_t)18 * HID);
  float* w_g  = alloc(HID);
  float* xr   = alloc(NN);
  float* sS   = alloc(NN);
  float* sD   = alloc(NN);
  float* mxN  = alloc(NN);
  float* sumN = alloc(NN);
  float* aN   = alloc(NN);
  float* a_node = alloc(NN);
  float* aE   = alloc(NE);
  float* mxG  = alloc(NG);
  float* sumG = alloc(NG);
  float* a_g  = alloc(NG);
  float* OUTa = alloc(GB);
  float* OUTb = alloc(GB);
  float* HM   = alloc(GB);
  (void)n_in; (void)in_sizes; (void)out_size;
  if (ws_size < off * sizeof(float)) return;  // fail loud, not with a GPU fault

  const int* dstArr = edge_index + NE;
  dim3 blk(256);
  auto g1 = [](long n) { return dim3((unsigned)((n + 255) / 256)); };
  auto gw = [](long waves) { return dim3((unsigned)((waves * 64 + 255) / 256)); };
  const long NBt = (long)NB, EBt = (long)NE * HID, GBt = (long)GB;
  // 1D XCD-grouped grids for the MFMA kernels (v1 tiles: hgemm 128x128, gru 64x64)
  const int MtH = (NN + 127) / 128;                       // 235
  const dim3 gH((unsigned)(8 * 3 * ((MtH + 7) / 8)));     // 720
  const int MtR = (NN + 63) / 64;                         // 469
  const dim3 gR((unsigned)(8 * 6 * ((MtR + 7) / 8)));     // 2832
  const int MtGH = (NG + 127) / 128;                      // 10
  const dim3 gF((unsigned)(8 * 6 * ((MtGH + 7) / 8)));    // 96   (Nn=OUTD)
  const int MtGR = (NG + 63) / 64;                        // 19
  const dim3 gRG((unsigned)(8 * 6 * ((MtGR + 7) / 8)));   // 144

  // ---- weight prep: f16 PF-packed copies ----
  hipLaunchKernelGGL(k_wpack, g1((long)HID * HID), blk, 0, stream, gl1_W, W1p, HID, HID);
  hipLaunchKernelGGL(k_wpack, g1((long)HID * HID), blk, 0, stream, gl2_W, W2p, HID, HID);
  hipLaunchKernelGGL(k_wpack, g1((long)HID * HID), blk, 0, stream, gat_W, Wgatp, HID, HID);
  hipLaunchKernelGGL(k_wpack, g1((long)HID * HID), blk, 0, stream, mol_W, Wmolp, HID, HID);
  hipLaunchKernelGGL(k_wpack, g1((long)3 * HID * HID), blk, 0, stream, gru1_Wi, Wg1ip, HID, 3 * HID);
  hipLaunchKernelGGL(k_wpack, g1((long)3 * HID * HID), blk, 0, stream, gru1_Wh, Wg1hp, HID, 3 * HID);
  hipLaunchKernelGGL(k_wpack, g1((long)3 * HID * HID), blk, 0, stream, gru2_Wi, Wg2ip, HID, 3 * HID);
  hipLaunchKernelGGL(k_wpack, g1((long)3 * HID * HID), blk, 0, stream, gru2_Wh, Wg2hp, HID, 3 * HID);
  hipLaunchKernelGGL(k_wpack, g1((long)3 * HID * HID), blk, 0, stream, mgru_Wi, Wmgip, HID, 3 * HID);
  hipLaunchKernelGGL(k_wpack, g1((long)3 * HID * HID), blk, 0, stream, mgru_Wh, Wmghp, HID, 3 * HID);
  hipLaunchKernelGGL(k_wpack, g1((long)HID * OUTD), blk, 0, stream, lin2_W, Wl2p, HID, OUTD);

  // ---- tables ----
  hipLaunchKernelGGL(k_gemm, dim3(HID / 64, 3), blk, 0, stream,
                     x_emb, lin1_W, nullptr, T1, 178, HID, EMB, 0);
  hipLaunchKernelGGL(k_gemm, dim3(HID / 64, 1), blk, 0, stream,
                     e_emb, gl1_W + (size_t)HID * HID, nullptr, Te, 18, HID, EMB, 0);
  // w_g = mol_W @ mol_ad  (a_g = out @ w_g; kills 3 mol hgemms by associativity)
  hipLaunchKernelGGL(k_rowdot, gw(HID), blk, 0, stream, mol_W, mol_ad, w_g, HID);

  // ---- x1 ----
  hipLaunchKernelGGL(k_node_embed, g1(NBt), blk, 0, stream, x_idx, T1, lin1_b, A, H1, NBt);

  // ---- GATEConv ----
  hipLaunchKernelGGL(k_hgemm, gH, blk, 0, stream, H1, W1p, nullptr, B, (f16*)nullptr, NN, HID, 0); // P
  hipLaunchKernelGGL(k_rowdot, gw(NN), blk, 0, stream, A, att_r, xr, NN);
  hipMemsetAsync(mxN, 0xFF, NN * sizeof(float), stream);
  hipLaunchKernelGGL(k_gate_att, gw(NE), blk, 0, stream, B, Te, edge_index, eai, att_l, xr, aE, mxN, NE);
  hipMemsetAsync(sumN, 0, NN * sizeof(float), stream);
  hipLaunchKernelGGL(k_seg_exp, g1(NE), blk, 0, stream, aE, dstArr, mxN, sumN, NE);
  hipMemsetAsync(C, 0, NB * sizeof(float), stream);
  hipLaunchKernelGGL(k_scatter_edge, g1(EBt), blk, 0, stream, B, Te, edge_index, eai, aE, sumN, C, EBt);
  hipLaunchKernelGGL(k_f2h_pf, g1(NBt), blk, 0, stream, C, H2, NBt);
  hipLaunchKernelGGL(k_hgemm, gH, blk, 0, stream, H2, W2p, gate_b, (float*)nullptr, H3, NN, HID, 2); // elu(h)
  // GRU1: x2 -> H2 (f16 PF only); h-state = H1 (PF)
  hipLaunchKernelGGL(k_gru_hgemm, gR, blk, 0, stream, H3, H1, Wg1ip, Wg1hp,
                     gru1_bi, gru1_bh, (float*)nullptr, H2, NN);

  // ---- GAT layer ----
  hipLaunchKernelGGL(k_hgemm, gH, blk, 0, stream, H2, Wgatp, nullptr, B, (f16*)nullptr, NN, HID, 0); // XL
  hipLaunchKernelGGL(k_rowdot2, gw(NN), blk, 0, stream, B, gat_as, gat_ad, sS, sD, NN);
  hipMemsetAsync(mxN, 0xFF, NN * sizeof(float), stream);
  hipLaunchKernelGGL(k_gat_att, g1(NE), blk, 0, stream, sS, sD, edge_index, aE, mxN, NE);
  hipMemsetAsync(sumN, 0, NN * sizeof(float), stream);
  hipLaunchKernelGGL(k_seg_exp, g1(NE), blk, 0, stream, aE, dstArr, mxN, sumN, NE);
  hipMemsetAsync(A, 0, NB * sizeof(float), stream);
  hipLaunchKernelGGL(k_scatter_gat, g1(EBt), blk, 0, stream, B, aE, sumN, edge_index, A, EBt);
  hipLaunchKernelGGL(k_bias_act, g1(NBt), blk, 0, stream, A, gat_b, H1, NBt, 2); // A=elu, H1=PF
  // GRU2: x3 -> B (f32) + H3 (f16 PF); h-state = H2 (PF)
  hipLaunchKernelGGL(k_gru_hgemm, gR, blk, 0, stream, H1, H2, Wg2ip, Wg2hp,
                     gru2_bi, gru2_bh, B, H3, NN);

  // ---- molecule readout ----
  hipMemsetAsync(OUTa, 0, GB * sizeof(float), stream);
  hipLaunchKernelGGL(k_scatter_sum, g1(NBt), blk, 0, stream, B, batch, OUTa, NBt);
  hipLaunchKernelGGL(k_bias_act, g1(GBt), blk, 0, stream, OUTa, (const float*)nullptr, OUTaPF, GBt, 3);
  hipLaunchKernelGGL(k_hgemm, gH, blk, 0, stream, H3, Wmolp, nullptr, A, (f16*)nullptr, NN, HID, 0); // XLm
  hipLaunchKernelGGL(k_rowdot, gw(NN), blk, 0, stream, A, mol_as, a_node, NN);

  float* cur = OUTa;   f16* curPF = OUTaPF;
  float* nxt = OUTb;   f16* nxtPF = OUTbPF;
  for (int t = 0; t < 3; t++) {
    hipLaunchKernelGGL(k_rowdot, gw(NG), blk, 0, stream, cur, w_g, a_g, NG); // a_g = cur @ w_g
    hipMemsetAsync(mxG, 0xFF, NG * sizeof(float), stream);
    hipLaunchKernelGGL(k_mol_att, g1(NN), blk, 0, stream, a_node, a_g, batch, aN, mxG, NN);
    hipMemsetAsync(sumG, 0, NG * sizeof(float), stream);
    hipLaunchKernelGGL(k_seg_exp, g1(NN), blk, 0, stream, aN, batch, mxG, sumG, NN);
    hipMemsetAsync(HM, 0, GB * sizeof(float), stream);
    hipLaunchKernelGGL(k_scatter_node, g1(NBt), blk, 0, stream, A, aN, sumG, batch, HM, NBt);
    hipLaunchKernelGGL(k_bias_act, g1(GBt), blk, 0, stream, HM, mol_b, HMp, GBt, 2);
    hipLaunchKernelGGL(k_gru_hgemm, gRG, blk, 0, stream, HMp, curPF, Wmgip, Wmghp,
                       mgru_bi, mgru_bh, nxt, nxtPF, NG);
    float* tf = cur; cur = nxt; nxt = tf;
    f16* th = curPF; curPF = nxtPF; nxtPF = th;
  }

  // ---- final projection: out = cur @ lin2_W + lin2_b ----
  hipLaunchKernelGGL(k_hgemm, gF, blk, 0, stream, curPF, Wl2p, lin2_b, outp, (f16*)nullptr, NG, OUTD, 0);
}